// Round 5
// baseline (501.414 us; speedup 1.0000x reference)
//
#include <hip/hip_runtime.h>
#include <hip/hip_bf16.h>
#include <math.h>
#include <stdint.h>

// ---------------------------------------------------------------------------
// VectorTokenizer: x ->(enc MLP)-> z -> categorical(threefry key(1)) tokens
//   -> z_q = sum of codebook rows -> (dec MLP) -> rec
// Outputs concatenated: z (4096*16384) | z_q (4096*256) | rec (4096*512), f32
//
// R5: (1) rotl via __builtin_rotateleft32 (v_alignbit, ~-30% threefry ops);
// (2) big GEMM retiled 64x512 (full vocab block per tile) with the gumbel
// top-2 sampler FUSED into the epilogue -> threefry VALU overlaps MFMA and
// the 268 MB z re-read disappears. Exact refine (w2t f32 rows) unchanged.
// ---------------------------------------------------------------------------

#define BATCH 4096
#define KTOK  32
#define VOCAB 512
#define DMODEL 512
#define ZDIM  16384
#define EDIM  256
#define MARGIN 0.03125f

typedef __attribute__((ext_vector_type(8))) short short8v;
typedef __attribute__((ext_vector_type(4))) float f32x4;

// ----------------------- threefry2x32 (JAX-compatible) ---------------------
__device__ __forceinline__ void threefry2x32(uint32_t k0, uint32_t k1,
                                             uint32_t x0, uint32_t x1,
                                             uint32_t& y0, uint32_t& y1) {
    uint32_t ks0 = k0, ks1 = k1, ks2 = k0 ^ k1 ^ 0x1BD11BDAu;
    x0 += ks0; x1 += ks1;
#define TFR(r) { x0 += x1; x1 = __builtin_rotateleft32(x1, r); x1 ^= x0; }
    TFR(13) TFR(15) TFR(26) TFR(6)
    x0 += ks1; x1 += ks2 + 1u;
    TFR(17) TFR(29) TFR(16) TFR(24)
    x0 += ks2; x1 += ks0 + 2u;
    TFR(13) TFR(15) TFR(26) TFR(6)
    x0 += ks0; x1 += ks1 + 3u;
    TFR(17) TFR(29) TFR(16) TFR(24)
    x0 += ks1; x1 += ks2 + 4u;
    TFR(13) TFR(15) TFR(26) TFR(6)
    x0 += ks2; x1 += ks0 + 5u;
#undef TFR
    y0 = x0; y1 = x1;
}

// exact path (refine): matches JAX bit-for-bit
__device__ __forceinline__ float jax_gumbel(uint64_t e) {
    const float TINY = 1.17549435e-38f;
    uint32_t y0, y1;
    threefry2x32(0u, 1u, (uint32_t)(e >> 32), (uint32_t)(e & 0xffffffffull), y0, y1);
    uint32_t bits = y0 ^ y1;
    float u = __uint_as_float(0x3f800000u | (bits >> 9)) - 1.0f;
    u = u * 1.0f + TINY;
    u = fmaxf(TINY, u);
    return -logf(-logf(u));
}

// fast path (filter only): |g_fast - g_exact| <~ 1e-4 << MARGIN
__device__ __forceinline__ float fast_gumbel(uint32_t e32) {
    const float TINY = 1.17549435e-38f;
    const float LN2 = 0.69314718056f;
    uint32_t y0, y1;
    threefry2x32(0u, 1u, 0u, e32, y0, y1);
    uint32_t bits = y0 ^ y1;
    float f = __uint_as_float(0x3f800000u | (bits >> 9));  // [1,2)
    float u = f - 1.0f;          // exact (Sterbenz)
    float d = 2.0f - f;          // exact = 1-u
    u = fmaxf(u, TINY);
    float e_hw = -LN2 * __builtin_amdgcn_logf(u);
    float e_poly = d * fmaf(d, fmaf(d, 0.33333333f, 0.5f), 1.0f);
    float e = (d < 0.002f) ? e_poly : e_hw;
    return -LN2 * __builtin_amdgcn_logf(e);
}

__device__ __forceinline__ unsigned short f32_to_bf16_rne(float f) {
    uint32_t u = __float_as_uint(f);
    uint32_t r = (u + 0x7fffu + ((u >> 16) & 1u)) >> 16;
    return (unsigned short)r;
}

// top-2 helpers (tie -> lower index wins, matching jnp.argmax)
__device__ __forceinline__ void top2_push(float& s1, float& s2, int& v1,
                                          float s, int v) {
    if (s > s1 || (s == s1 && v < v1)) { s2 = s1; s1 = s; v1 = v; }
    else s2 = fmaxf(s2, s);
}
__device__ __forceinline__ void top2_merge(float& s1, float& s2, int& v1,
                                           float os1, float os2, int ov1) {
    if (os1 > s1 || (os1 == s1 && ov1 < v1)) {
        s2 = fmaxf(s1, os2);
        s1 = os1; v1 = ov1;
    } else {
        s2 = fmaxf(s2, os1);
    }
}

__device__ __forceinline__ void gload16(const unsigned short* src,
                                        unsigned short* lds_base) {
    __builtin_amdgcn_global_load_lds(
        (const __attribute__((address_space(1))) unsigned int*)src,
        (__attribute__((address_space(3))) unsigned int*)lds_base, 16, 0, 0);
}

// ------------------ tiled f32 GEMM, 64x64 (small layers) -------------------
// k-ascending single fmaf chain per output => bit-exact vs np
template<bool RELU>
__global__ __launch_bounds__(256)
void gemm_f32_64(const float* __restrict__ A, const float* __restrict__ B,
                 const float* __restrict__ bias, float* __restrict__ C,
                 int M, int N, int K) {
    constexpr int BK = 16;
    __shared__ __align__(16) float As[BK][68];
    __shared__ __align__(16) float Bs[BK][68];

    const int tid = threadIdx.x;
    const int tx = tid % 16;
    const int ty = tid / 16;
    const int brow = blockIdx.y * 64;
    const int bcol = blockIdx.x * 64;

    float acc[4][4] = {};

    for (int k0 = 0; k0 < K; k0 += BK) {
        {
            int r = tid >> 2, c4 = tid & 3;
            float4 v = *(const float4*)&A[(size_t)(brow + r) * K + k0 + c4 * 4];
            As[c4 * 4 + 0][r] = v.x;
            As[c4 * 4 + 1][r] = v.y;
            As[c4 * 4 + 2][r] = v.z;
            As[c4 * 4 + 3][r] = v.w;
        }
        {
            int r = tid >> 4, c4 = tid & 15;
            *(float4*)&Bs[r][c4 * 4] = *(const float4*)&B[(size_t)(k0 + r) * N + bcol + c4 * 4];
        }
        __syncthreads();

#pragma unroll
        for (int kk = 0; kk < BK; ++kk) {
            float a[4], b[4];
            *(float4*)&a[0] = *(const float4*)&As[kk][ty * 4];
            *(float4*)&b[0] = *(const float4*)&Bs[kk][tx * 4];
#pragma unroll
            for (int i = 0; i < 4; ++i)
#pragma unroll
                for (int j = 0; j < 4; ++j)
                    acc[i][j] = fmaf(a[i], b[j], acc[i][j]);
        }
        __syncthreads();
    }

#pragma unroll
    for (int i = 0; i < 4; ++i) {
        int row = brow + ty * 4 + i;
        int col = bcol + tx * 4;
        float4 v;
        v.x = acc[i][0] + bias[col + 0];
        v.y = acc[i][1] + bias[col + 1];
        v.z = acc[i][2] + bias[col + 2];
        v.w = acc[i][3] + bias[col + 3];
        if (RELU) {
            v.x = fmaxf(v.x, 0.0f); v.y = fmaxf(v.y, 0.0f);
            v.z = fmaxf(v.z, 0.0f); v.w = fmaxf(v.w, 0.0f);
        }
        *(float4*)&C[(size_t)row * N + col] = v;
    }
}

// ---------------- tiled f32 GEMM, 128x128 (fallback big) -------------------
template<bool RELU>
__global__ __launch_bounds__(256)
void gemm_f32(const float* __restrict__ A, const float* __restrict__ B,
              const float* __restrict__ bias, float* __restrict__ C,
              int M, int N, int K) {
    constexpr int BM = 128, BN = 128, BK = 16, TM = 8, TN = 8;
    __shared__ __align__(16) float As[BK][BM + 4];
    __shared__ __align__(16) float Bs[BK][BN + 4];

    const int tid = threadIdx.x;
    const int tx = tid % (BN / TN);
    const int ty = tid / (BN / TN);
    const int brow = blockIdx.y * BM;
    const int bcol = blockIdx.x * BN;

    float acc[TM][TN] = {};

    for (int k0 = 0; k0 < K; k0 += BK) {
#pragma unroll
        for (int f = tid; f < BM * BK / 4; f += 256) {
            int r = f / (BK / 4);
            int c4 = f % (BK / 4);
            float4 v = *(const float4*)&A[(size_t)(brow + r) * K + k0 + c4 * 4];
            As[c4 * 4 + 0][r] = v.x;
            As[c4 * 4 + 1][r] = v.y;
            As[c4 * 4 + 2][r] = v.z;
            As[c4 * 4 + 3][r] = v.w;
        }
#pragma unroll
        for (int f = tid; f < BK * BN / 4; f += 256) {
            int r = f / (BN / 4);
            int c4 = f % (BN / 4);
            *(float4*)&Bs[r][c4 * 4] = *(const float4*)&B[(size_t)(k0 + r) * N + bcol + c4 * 4];
        }
        __syncthreads();

#pragma unroll
        for (int kk = 0; kk < BK; ++kk) {
            float a[TM], b[TN];
            *(float4*)&a[0] = *(const float4*)&As[kk][ty * TM];
            *(float4*)&a[4] = *(const float4*)&As[kk][ty * TM + 4];
            *(float4*)&b[0] = *(const float4*)&Bs[kk][tx * TN];
            *(float4*)&b[4] = *(const float4*)&Bs[kk][tx * TN + 4];
#pragma unroll
            for (int i = 0; i < TM; ++i)
#pragma unroll
                for (int j = 0; j < TN; ++j)
                    acc[i][j] = fmaf(a[i], b[j], acc[i][j]);
        }
        __syncthreads();
    }

#pragma unroll
    for (int i = 0; i < TM; ++i) {
        int row = brow + ty * TM + i;
#pragma unroll
        for (int j = 0; j < TN; j += 4) {
            int col = bcol + tx * TN + j;
            float4 v;
            v.x = acc[i][j + 0] + bias[col + 0];
            v.y = acc[i][j + 1] + bias[col + 1];
            v.z = acc[i][j + 2] + bias[col + 2];
            v.w = acc[i][j + 3] + bias[col + 3];
            if (RELU) {
                v.x = fmaxf(v.x, 0.0f); v.y = fmaxf(v.y, 0.0f);
                v.z = fmaxf(v.z, 0.0f); v.w = fmaxf(v.w, 0.0f);
            }
            *(float4*)&C[(size_t)row * N + col] = v;
        }
    }
}

// --------------------- f32 -> bf16 elementwise convert ---------------------
__global__ __launch_bounds__(256)
void cvt_to_bf16(const float* __restrict__ src, unsigned short* __restrict__ dst,
                 int n) {
    int i = blockIdx.x * 256 + threadIdx.x;
    if (i * 4 < n) {
        float4 v = *(const float4*)&src[i * 4];
        ushort4 o;
        o.x = f32_to_bf16_rne(v.x);
        o.y = f32_to_bf16_rne(v.y);
        o.z = f32_to_bf16_rne(v.z);
        o.w = f32_to_bf16_rne(v.w);
        *(ushort4*)&dst[i * 4] = o;
    }
}

// ---- f32 [R][C] -> bf16 [C][R] transpose, optionally also f32 [C][R] ------
__global__ __launch_bounds__(256)
void transpose_w2(const float* __restrict__ src, unsigned short* __restrict__ dstb,
                  float* __restrict__ dstf, int R, int C, int writeF) {
    __shared__ float tile[32][33];
    const int c0 = blockIdx.x * 32, r0 = blockIdx.y * 32;
    const int tx = threadIdx.x % 32, ty = threadIdx.x / 32;
#pragma unroll
    for (int i = ty; i < 32; i += 8)
        tile[i][tx] = src[(size_t)(r0 + i) * C + c0 + tx];
    __syncthreads();
#pragma unroll
    for (int i = ty; i < 32; i += 8) {
        float v = tile[tx][i];
        size_t o = (size_t)(c0 + i) * R + r0 + tx;
        dstb[o] = f32_to_bf16_rne(v);
        if (writeF) dstf[o] = v;
    }
}

// ---------------- fused bf16 MFMA GEMM + gumbel top-2 sampler --------------
// Tile 64(batch) x 512(= full vocab of one token block); 8 waves, wave-tile
// 32x128. LDS layout [kq][row][8] (2-way-max bank pattern, gload_lds linear).
// Epilogue: z write + fast-gumbel top-2 per row, tokens/s1v/amb emitted.
__global__ __launch_bounds__(512, 4)
void gemm_fused_sample(const unsigned short* __restrict__ A,
                       const unsigned short* __restrict__ Bt,
                       const float* __restrict__ bias,
                       float* __restrict__ C,
                       int* __restrict__ tokens, float* __restrict__ s1v,
                       int* __restrict__ amb, int* __restrict__ ambCount) {
    __shared__ unsigned short As[4 * 64 * 8];    // [kq][64 rows][8]
    __shared__ unsigned short Bs[4 * 512 * 8];   // [kq][512 rows][8]
    __shared__ float redS1[64][4];
    __shared__ float redS2[64][4];
    __shared__ int   redV[64][4];

    // XCD-aware swizzle; consecutive swz share bx (B-panel L2 reuse)
    const int lid = blockIdx.x;                  // 2048 blocks
    const int swz = (lid & 7) * 256 + (lid >> 3);
    const int bx = swz >> 6;                     // kb  0..31
    const int by = swz & 63;                     // batch tile 0..63

    const int tid = threadIdx.x;
    const int wid = tid >> 6;
    const int lane = tid & 63;
    const int wr2 = wid >> 2, wc = wid & 3;
    const int l15 = lane & 15, lq = lane >> 4;
    const int brow = by * 64;
    const int bcol = bx * 512;

    const unsigned short* aSrc = A + (size_t)(brow + lane) * DMODEL;
    const unsigned short* bSrc = Bt + (size_t)(bcol + wid * 64 + lane) * DMODEL;

    f32x4 acc[2][8];
#pragma unroll
    for (int m = 0; m < 2; ++m)
#pragma unroll
        for (int n = 0; n < 8; ++n) acc[m][n] = (f32x4){0.f, 0.f, 0.f, 0.f};

    for (int k0 = 0; k0 < DMODEL; k0 += 32) {
        if (wid < 4)
            gload16(aSrc + k0 + wid * 8, As + wid * 512);
#pragma unroll
        for (int kq = 0; kq < 4; ++kq)
            gload16(bSrc + k0 + kq * 8, Bs + kq * 4096 + wid * 512);
        __syncthreads();

        short8v af[2], bf[8];
#pragma unroll
        for (int m = 0; m < 2; ++m)
            af[m] = *(const short8v*)&As[lq * 512 + (wr2 * 32 + m * 16 + l15) * 8];
#pragma unroll
        for (int n = 0; n < 8; ++n)
            bf[n] = *(const short8v*)&Bs[lq * 4096 + (wc * 128 + n * 16 + l15) * 8];
#pragma unroll
        for (int m = 0; m < 2; ++m)
#pragma unroll
            for (int n = 0; n < 8; ++n)
                acc[m][n] = __builtin_amdgcn_mfma_f32_16x16x32_bf16(
                    af[m], bf[n], acc[m][n], 0, 0, 0);
        __syncthreads();
    }

    // ---------------- epilogue: z write + fused top-2 sampling -------------
    float s1[2][4], s2[2][4];
    int v1[2][4];
#pragma unroll
    for (int m = 0; m < 2; ++m)
#pragma unroll
        for (int r = 0; r < 4; ++r) {
            s1[m][r] = -INFINITY; s2[m][r] = -INFINITY; v1[m][r] = VOCAB;
        }

#pragma unroll
    for (int m = 0; m < 2; ++m) {
#pragma unroll
        for (int n = 0; n < 8; ++n) {
            const int col = wc * 128 + n * 16 + l15;     // vocab index v
            const float bv = bias[bcol + col];
#pragma unroll
            for (int r = 0; r < 4; ++r) {
                const int row = wr2 * 32 + m * 16 + lq * 4 + r;
                const float val = acc[m][n][r] + bv;
                C[(size_t)(brow + row) * ZDIM + bcol + col] = val;
                const uint32_t t = (uint32_t)(brow + row) * KTOK + bx;
                const float g = fast_gumbel(t * (uint32_t)VOCAB + (uint32_t)col);
                top2_push(s1[m][r], s2[m][r], v1[m][r], val + g, col);
            }
        }
    }

    // butterfly across the 16 l15 lanes (same lq => same rows)
#pragma unroll
    for (int off = 1; off < 16; off <<= 1) {
#pragma unroll
        for (int m = 0; m < 2; ++m)
#pragma unroll
            for (int r = 0; r < 4; ++r) {
                float os1 = __shfl_xor(s1[m][r], off);
                float os2 = __shfl_xor(s2[m][r], off);
                int   ov1 = __shfl_xor(v1[m][r], off);
                top2_merge(s1[m][r], s2[m][r], v1[m][r], os1, os2, ov1);
            }
    }
    if (l15 == 0) {
#pragma unroll
        for (int m = 0; m < 2; ++m)
#pragma unroll
            for (int r = 0; r < 4; ++r) {
                const int row = wr2 * 32 + m * 16 + lq * 4 + r;
                redS1[row][wc] = s1[m][r];
                redS2[row][wc] = s2[m][r];
                redV[row][wc]  = v1[m][r];
            }
    }
    __syncthreads();

    if (tid < 64) {
        const int row = tid;
        float S1 = -INFINITY, S2 = -INFINITY;
        int V1 = VOCAB;
#pragma unroll
        for (int w = 0; w < 4; ++w)
            top2_merge(S1, S2, V1, redS1[row][w], redS2[row][w], redV[row][w]);
        const uint32_t t = (uint32_t)(brow + row) * KTOK + bx;
        tokens[t] = V1;
        s1v[t] = S1;
        if (S1 - S2 < MARGIN) {
            int idx = atomicAdd(ambCount, 1);
            amb[idx] = (int)t;
        }
    }
}

// ------ refine v2: w2t f32 rows, ballot-compacted candidates ---------------
__global__ __launch_bounds__(64)
void refine_tokens2(const float* __restrict__ z, const float* __restrict__ h,
                    const float* __restrict__ w2t, const float* __restrict__ eb2,
                    const int* __restrict__ amb, const int* __restrict__ ambCount,
                    const float* __restrict__ s1v, int* __restrict__ tok) {
    __shared__ float hrow[DMODEL];
    __shared__ int candv[64];
    const int cnt = *ambCount;
    const int lane = threadIdx.x;

    for (int i = blockIdx.x; i < cnt; i += gridDim.x) {
        const int t = amb[i];
        const int b = t >> 5;
        const int kb = t & 31;
        const float* zr = z + (size_t)t * VOCAB;
        const float s1 = s1v[t];

        {
            float4 hv0 = *(const float4*)&h[(size_t)b * DMODEL + lane * 8];
            float4 hv1 = *(const float4*)&h[(size_t)b * DMODEL + lane * 8 + 4];
            *(float4*)&hrow[lane * 8] = hv0;
            *(float4*)&hrow[lane * 8 + 4] = hv1;
        }

        int base = 0;
#pragma unroll
        for (int half = 0; half < 2; ++half) {
            int e0 = half * 256 + lane * 4;
            float4 zv = *(const float4*)&zr[e0];
            float zs[4] = {zv.x, zv.y, zv.z, zv.w};
#pragma unroll
            for (int j = 0; j < 4; ++j) {
                int v = e0 + j;
                float s = zs[j] + fast_gumbel((uint32_t)t * VOCAB + v);
                bool pred = (s >= s1 - MARGIN);
                unsigned long long mask = __ballot(pred);
                if (pred) {
                    int slot = base + __popcll(mask & ((1ull << lane) - 1ull));
                    if (slot < 64) candv[slot] = v;
                }
                base += __popcll(mask);
            }
        }
        __syncthreads();
        const int ncand = base < 64 ? base : 64;

        float bestE = -INFINITY;
        int bestV = VOCAB;
        if (lane < ncand) {
            const int v = candv[lane];
            const int n = kb * VOCAB + v;
            const float* wr_ = w2t + (size_t)n * DMODEL;
            float acc = 0.f;
#pragma unroll 8
            for (int k = 0; k < DMODEL; ++k)
                acc = fmaf(hrow[k], wr_[k], acc);
            bestE = acc + eb2[n] + jax_gumbel((uint64_t)t * VOCAB + v);
            bestV = v;
        }
#pragma unroll
        for (int off = 32; off > 0; off >>= 1) {
            float oe = __shfl_down(bestE, off);
            int ov = __shfl_down(bestV, off);
            if (oe > bestE || (oe == bestE && ov < bestV)) { bestE = oe; bestV = ov; }
        }
        if (lane == 0) tok[t] = bestV;
        __syncthreads();
    }
}

// --------- refine v1 (fallback when ws too small for w2t) ------------------
__global__ __launch_bounds__(64)
void refine_tokens(const float* __restrict__ z, const float* __restrict__ h,
                   const float* __restrict__ w2, const float* __restrict__ eb2,
                   const int* __restrict__ amb, const int* __restrict__ ambCount,
                   const float* __restrict__ s1v, int* __restrict__ tok) {
    const int cnt = *ambCount;
    const int lane = threadIdx.x;
    for (int i = blockIdx.x; i < cnt; i += gridDim.x) {
        const int t = amb[i];
        const int b = t >> 5;
        const int kb = t & 31;
        const float* zr = z + (size_t)t * VOCAB;
        const float s1 = s1v[t];
        float bestE = -INFINITY;
        int bestV = VOCAB;
#pragma unroll 1
        for (int r = 0; r < 8; ++r) {
            const int v = r * 64 + lane;
            const float g = jax_gumbel((uint64_t)t * VOCAB + v);
            const float sbf = zr[v] + g;
            float ex = -INFINITY;
            if (sbf >= s1 - MARGIN) {
                const float* hr = h + (size_t)b * DMODEL;
                const float* wcol = w2 + (size_t)(kb * VOCAB + v);
                float acc = 0.f;
#pragma unroll 8
                for (int k = 0; k < DMODEL; ++k)
                    acc = fmaf(hr[k], wcol[(size_t)k * ZDIM], acc);
                ex = acc + eb2[kb * VOCAB + v] + g;
            }
            if (ex > bestE || (ex == bestE && v < bestV)) { bestE = ex; bestV = v; }
        }
#pragma unroll
        for (int off = 32; off > 0; off >>= 1) {
            float oe = __shfl_down(bestE, off);
            int ov = __shfl_down(bestV, off);
            if (oe > bestE || (oe == bestE && ov < bestV)) { bestE = oe; bestV = ov; }
        }
        if (lane == 0) tok[t] = bestV;
    }
}

// ----------------- simple sampler (ws-too-small fallback) ------------------
__global__ __launch_bounds__(256)
void sample_tokens_simple(const float* __restrict__ z, int* __restrict__ tokens) {
    const int wave = threadIdx.x >> 6;
    const int lane = threadIdx.x & 63;
    const size_t t = (size_t)blockIdx.x * 4 + wave;
    const float* zr = z + t * VOCAB;
    float zv[8];
    *(float4*)&zv[0] = *(const float4*)&zr[lane * 8];
    *(float4*)&zv[4] = *(const float4*)&zr[lane * 8 + 4];
    const uint64_t ebase = t * (uint64_t)VOCAB + (uint64_t)lane * 8;
    float best = -INFINITY;
    int bestv = 0;
#pragma unroll
    for (int j = 0; j < 8; ++j) {
        float g = jax_gumbel(ebase + j);
        float s = zv[j] + g;
        int v = lane * 8 + j;
        if (s > best || (s == best && v < bestv)) { best = s; bestv = v; }
    }
#pragma unroll
    for (int off = 32; off > 0; off >>= 1) {
        float ob = __shfl_down(best, off);
        int ov = __shfl_down(bestv, off);
        if (ob > best || (ob == best && ov < bestv)) { best = ob; bestv = ov; }
    }
    if (lane == 0) tokens[t] = bestv;
}

__global__ __launch_bounds__(64)
void zero_count(int* p) { if (threadIdx.x == 0) *p = 0; }

// ------------------------- z_q gather (1 block / row) ----------------------
__global__ __launch_bounds__(256)
void gather_zq(const int* __restrict__ tokens, const float* __restrict__ codebook,
               float* __restrict__ zq) {
    const int b = blockIdx.x;
    const int d = threadIdx.x;
    float s = 0.0f;
#pragma unroll
    for (int k = 0; k < KTOK; ++k) {
        int tok = tokens[b * KTOK + k];
        s += codebook[(size_t)(k * VOCAB + tok) * EDIM + d];
    }
    zq[(size_t)b * EDIM + d] = s;
}

// ------------------------------- launcher ----------------------------------
extern "C" void kernel_launch(void* const* d_in, const int* in_sizes, int n_in,
                              void* d_out, int out_size, void* d_ws, size_t ws_size,
                              hipStream_t stream) {
    const float* x   = (const float*)d_in[0];
    const float* ew1 = (const float*)d_in[1];
    const float* eb1 = (const float*)d_in[2];
    const float* ew2 = (const float*)d_in[3];
    const float* eb2 = (const float*)d_in[4];
    const float* cb  = (const float*)d_in[5];
    const float* dw1 = (const float*)d_in[6];
    const float* db1 = (const float*)d_in[7];
    const float* dw2 = (const float*)d_in[8];
    const float* db2 = (const float*)d_in[9];

    float* out = (float*)d_out;
    float* z   = out;
    float* zq  = out + (size_t)BATCH * ZDIM;
    float* rec = zq + (size_t)BATCH * EDIM;

    char* ws = (char*)d_ws;
    float* h    = (float*)(ws);                               // 8 MB
    float* h2   = (float*)(ws + 8388608);                     // 8 MB
    unsigned short* hb   = (unsigned short*)(ws + 16777216);  // 4 MB
    unsigned short* w2bt = (unsigned short*)(ws + 20971520);  // 16 MB
    float* w2t  = (float*)(ws + 37748736);                    // 32 MB (fast2)
    const size_t WS_NEED1 = 39321856;
    const size_t WS_NEED2 = 37748736 + 33554432 + 1572864 + 256;  // ~72.9 MB
    const bool fast  = ws_size >= WS_NEED1;
    const bool fast2 = ws_size >= WS_NEED2;
    char* tail = fast2 ? (ws + 37748736 + 33554432) : (ws + 37748736);
    int*   tok  = (int*)(tail);
    float* s1v  = (float*)(tail + 524288);
    int*   amb  = (int*)(tail + 1048576);
    int*   cnt  = (int*)(tail + 1572864);

    dim3 blk(256);

    // encoder layer 1 (f32 exact — feeds the exact-recompute path)
    gemm_f32_64<true ><<<dim3(DMODEL / 64, BATCH / 64), blk, 0, stream>>>(
        x, ew1, eb1, h, BATCH, DMODEL, DMODEL);

    if (fast) {
        cvt_to_bf16<<<dim3(BATCH * DMODEL / 4 / 256), blk, 0, stream>>>(
            h, hb, BATCH * DMODEL);
        transpose_w2<<<dim3(ZDIM / 32, DMODEL / 32), blk, 0, stream>>>(
            ew2, w2bt, w2t, DMODEL, ZDIM, fast2 ? 1 : 0);
        zero_count<<<dim3(1), dim3(64), 0, stream>>>(cnt);
        gemm_fused_sample<<<dim3(2048), dim3(512), 0, stream>>>(
            hb, w2bt, eb2, z, tok, s1v, amb, cnt);
        if (fast2) {
            refine_tokens2<<<dim3(4096), dim3(64), 0, stream>>>(
                z, h, w2t, eb2, amb, cnt, s1v, tok);
        } else {
            refine_tokens<<<dim3(2048), dim3(64), 0, stream>>>(
                z, h, ew2, eb2, amb, cnt, s1v, tok);
        }
    } else {
        gemm_f32<false><<<dim3(ZDIM / 128, BATCH / 128), blk, 0, stream>>>(
            h, ew2, eb2, z, BATCH, ZDIM, DMODEL);
        sample_tokens_simple<<<dim3(BATCH * KTOK / 4), blk, 0, stream>>>(z, tok);
    }

    gather_zq<<<dim3(BATCH), blk, 0, stream>>>(tok, cb, zq);

    // decoder (f32 exact)
    gemm_f32_64<true ><<<dim3(DMODEL / 64, BATCH / 64), blk, 0, stream>>>(
        zq, dw1, db1, h2, BATCH, DMODEL, EDIM);
    gemm_f32_64<false><<<dim3(DMODEL / 64, BATCH / 64), blk, 0, stream>>>(
        h2, dw2, db2, rec, BATCH, DMODEL, DMODEL);
}